// Round 2
// baseline (53.963 us; speedup 1.0000x reference)
//
#include <hip/hip_runtime.h>

// LogitDistance: out = sum_{b} sum_{i<j} |p[b,i]-p[b,j]| / (ntriu * B * N)
// Triangle tiling: 256x256 tiles, blocks for J>=I only; diagonal tiles
// count each unordered pair twice -> weight 0.5. Fused final reduce via
// atomic-counter last-block pattern (counter zeroed by a 4B memset node).

#define NN 4096
#define TILE 256
#define TPD (NN / TILE)                    // 16 tiles per dim
#define TRI_TILES (TPD * (TPD + 1) / 2)    // 136 triangle tiles per row
#define THREADS 256

__global__ __launch_bounds__(THREADS) void pairdist_tri(
    const float* __restrict__ pred, int nblocks,
    float* __restrict__ partials, int* __restrict__ cnt,
    float* __restrict__ out, double scale)
{
    const int blk  = blockIdx.x;
    const int b    = blk / TRI_TILES;
    int rem = blk % TRI_TILES;
    int I = 0;
    while (rem >= TPD - I) { rem -= TPD - I; ++I; }
    const int J = I + rem;

    const float* __restrict__ row  = pred + (size_t)b * NN;
    const float* __restrict__ jrow = row + J * TILE;   // block-uniform base
    const float pi = row[I * TILE + threadIdx.x];      // coalesced

    float a0 = 0.f, a1 = 0.f, a2 = 0.f, a3 = 0.f;
#pragma unroll 8
    for (int j = 0; j < TILE; j += 4) {
        // uniform-address float4 load: broadcasts via L1, zero VALU cost
        float4 jv = *reinterpret_cast<const float4*>(jrow + j);
        a0 += fabsf(pi - jv.x);
        a1 += fabsf(pi - jv.y);
        a2 += fabsf(pi - jv.z);
        a3 += fabsf(pi - jv.w);
    }
    float s = (a0 + a1) + (a2 + a3);
    if (I == J) s *= 0.5f;   // same-tile pairs counted twice

    // wave-64 reduce
#pragma unroll
    for (int off = 32; off > 0; off >>= 1)
        s += __shfl_down(s, off, 64);

    __shared__ float sw[THREADS / 64];
    __shared__ int isLast;
    const int lane = threadIdx.x & 63;
    const int wid  = threadIdx.x >> 6;
    if (lane == 0) sw[wid] = s;
    if (threadIdx.x == 0) isLast = 0;
    __syncthreads();

    if (threadIdx.x == 0) {
        float bs = 0.f;
#pragma unroll
        for (int w = 0; w < THREADS / 64; ++w) bs += sw[w];
        partials[blk] = bs;
        __threadfence();                       // release partial
        int old = atomicAdd(cnt, 1);           // device scope
        if (old == nblocks - 1) isLast = 1;
    }
    __syncthreads();

    if (isLast) {   // block-uniform branch; result independent of WHICH block
        __threadfence();                       // acquire
        double ds = 0.0;
        for (int i = threadIdx.x; i < nblocks; i += THREADS)
            ds += (double)__hip_atomic_load(&partials[i], __ATOMIC_RELAXED,
                                            __HIP_MEMORY_SCOPE_AGENT);
        __shared__ double sd[THREADS];
        sd[threadIdx.x] = ds;
        __syncthreads();
        for (int off = THREADS / 2; off > 0; off >>= 1) {
            if (threadIdx.x < off) sd[threadIdx.x] += sd[threadIdx.x + off];
            __syncthreads();
        }
        if (threadIdx.x == 0) out[0] = (float)(sd[0] * scale);
    }
}

extern "C" void kernel_launch(void* const* d_in, const int* in_sizes, int n_in,
                              void* d_out, int out_size, void* d_ws, size_t ws_size,
                              hipStream_t stream) {
    const float* pred = (const float*)d_in[0];
    const int total = in_sizes[0];
    const int B = total / NN;                 // 16
    const int nblocks = B * TRI_TILES;        // 2176

    float* partials = (float*)d_ws;
    int*   cnt      = (int*)((char*)d_ws + (size_t)nblocks * sizeof(float));

    // counter must be zero each call (d_ws poisoned 0xAA, never re-poisoned)
    hipMemsetAsync(cnt, 0, sizeof(int), stream);

    const double ntriu = (double)NN * (double)(NN - 1) * 0.5;
    const double scale = 1.0 / (ntriu * (double)B * (double)NN);

    pairdist_tri<<<nblocks, THREADS, 0, stream>>>(
        pred, nblocks, partials, cnt, (float*)d_out, scale);
}

// Round 3
// 25.596 us; speedup vs baseline: 2.1083x; 2.1083x over previous
//
#include <hip/hip_runtime.h>

// LogitDistance: out = sum_b sum_{i<j} |p[b,i]-p[b,j]| / (ntriu * B * N)
//
// Exact triangle partition at (2048-i x 128-j) granularity:
//   unit (ih, jh) kept iff jh >= 16*ih.
//   w=1   units: j-seg strictly above i-chunk  (cross-chunk pairs, once each)
//   w=0.5 units: j-seg inside i-chunk          (same-chunk pairs, twice each)
// 48 units per batch row x 16 rows = 768 equal-cost blocks (= 3 x 256 CUs).
//
// Round-2 lessons applied: j-tile staged in LDS (64 VALU ops per ds_read_b128,
// broadcast -> conflict-free), NO fences; single dispatch with one f32
// atomicAdd of the pre-scaled block partial (error bound 768*ulp(2.8e-4)
// ~ 2e-8 for any add order, threshold is 5.5e-6).

#define NN   4096
#define THREADS 256
#define R    8      // i-values per thread (i-chunk = 2048)
#define JSEG 128    // j-values staged in LDS
#define UPB  48     // triangle units per batch row

__global__ __launch_bounds__(THREADS) void pairdist_tri(
    const float* __restrict__ pred, float* __restrict__ out, float scale)
{
    const int blk = blockIdx.x;
    const int b   = blk / UPB;
    const int u   = blk % UPB;

    // unit -> (ih, jh, w):  u<32: ih=0, jh=u;  u>=32: ih=1, jh=u-16
    const int   ih = (u < 32) ? 0 : 1;
    const int   jh = (u < 32) ? u : (u - 16);
    const float w  = (u >= 16 && u < 32) ? 1.0f : 0.5f;

    const float* __restrict__ row = pred + (size_t)b * NN;

    __shared__ float sj[JSEG];
    if (threadIdx.x < JSEG)
        sj[threadIdx.x] = row[jh * JSEG + threadIdx.x];

    // this thread's 8 i-values (coalesced, stride-256 groups)
    float pi[R];
#pragma unroll
    for (int k = 0; k < R; ++k)
        pi[k] = row[ih * (THREADS * R) + k * THREADS + threadIdx.x];

    __syncthreads();

    float acc[R];
#pragma unroll
    for (int k = 0; k < R; ++k) acc[k] = 0.0f;

    // 64 VALU ops per broadcast ds_read_b128; 8 independent dep chains
#pragma unroll 4
    for (int j = 0; j < JSEG; j += 4) {
        float4 jv = *reinterpret_cast<const float4*>(&sj[j]);
#pragma unroll
        for (int k = 0; k < R; ++k) {
            acc[k] += fabsf(pi[k] - jv.x);
            acc[k] += fabsf(pi[k] - jv.y);
            acc[k] += fabsf(pi[k] - jv.z);
            acc[k] += fabsf(pi[k] - jv.w);
        }
    }

    float s = 0.0f;
#pragma unroll
    for (int k = 0; k < R; ++k) s += acc[k];

    // wave-64 butterfly reduce
#pragma unroll
    for (int off = 32; off > 0; off >>= 1)
        s += __shfl_down(s, off, 64);

    __shared__ float sw[THREADS / 64];
    const int lane = threadIdx.x & 63;
    const int wid  = threadIdx.x >> 6;
    if (lane == 0) sw[wid] = s;
    __syncthreads();

    if (threadIdx.x == 0) {
        float bs = 0.0f;
#pragma unroll
        for (int v = 0; v < THREADS / 64; ++v) bs += sw[v];
        atomicAdd(out, bs * w * scale);   // device-scope, no fence needed
    }
}

extern "C" void kernel_launch(void* const* d_in, const int* in_sizes, int n_in,
                              void* d_out, int out_size, void* d_ws, size_t ws_size,
                              hipStream_t stream) {
    const float* pred = (const float*)d_in[0];
    const int total = in_sizes[0];
    const int B = total / NN;              // 16
    const int nblocks = B * UPB;           // 768 = 3 * 256

    // d_out must start at zero each replay (poisoned 0xAA once, never restored)
    hipMemsetAsync(d_out, 0, (size_t)out_size * sizeof(float), stream);

    const double ntriu = (double)NN * (double)(NN - 1) * 0.5;
    const float scale = (float)(1.0 / (ntriu * (double)B * (double)NN));

    pairdist_tri<<<nblocks, THREADS, 0, stream>>>(pred, (float*)d_out, scale);
}